// Round 7
// baseline (1332.450 us; speedup 1.0000x reference)
//
#include <hip/hip_runtime.h>

typedef _Float16 half2f __attribute__((ext_vector_type(2)));
typedef _Float16 half8  __attribute__((ext_vector_type(8)));
typedef float    floatx4 __attribute__((ext_vector_type(4)));

#define HID 128   // hidden size
#define G4  512   // 4*HID
#define DIN 64    // input dim

__device__ __forceinline__ float fdot2(half2f a, half2f b, float c) {
  return __builtin_amdgcn_fdot2(a, b, c, false);
}
__device__ __forceinline__ half2f as_h2(unsigned int u) {
  return __builtin_bit_cast(half2f, u);
}
__device__ __forceinline__ half2f mk2(float a, float b) {
  half2f r; r.x = (_Float16)a; r.y = (_Float16)b; return r;
}
__device__ __forceinline__ half8 cvt8(float4 a, float4 b) {
  half8 r;
  r[0] = (_Float16)a.x; r[1] = (_Float16)a.y;
  r[2] = (_Float16)a.z; r[3] = (_Float16)a.w;
  r[4] = (_Float16)b.x; r[5] = (_Float16)b.y;
  r[6] = (_Float16)b.z; r[7] = (_Float16)b.w;
  return r;
}
__device__ __forceinline__ float sigmoidf_fast(float x) {
  return __builtin_amdgcn_rcpf(1.0f + __expf(-x));
}
__device__ __forceinline__ float tanhf_fast(float x) {
  return 2.0f * __builtin_amdgcn_rcpf(1.0f + __expf(-2.0f * x)) - 1.0f;
}
template <int CTRL>
__device__ __forceinline__ float dpp_bcast(float x) {
  int m = __builtin_amdgcn_update_dpp(0, __builtin_bit_cast(int, x),
                                      CTRL, 0xF, 0xF, true);
  return __builtin_bit_cast(float, m);
}
#define QP_B0 0x00
#define QP_B1 0x55
#define QP_B2 0xAA
#define QP_B3 0xFF

// Barrier that does NOT drain vmcnt (prefetch loads stay in flight).
// lgkmcnt(0) drains this wave's DS ops before the barrier.
__device__ __forceinline__ void barrier_lgkm() {
  asm volatile("s_waitcnt lgkmcnt(0)" ::: "memory");
  __builtin_amdgcn_s_barrier();
  asm volatile("" ::: "memory");
}

// ---------------------------------------------------------------------------
// Phase 1: x_proj (+bias), fp16, stored in the scan's MFMA-blocked layout:
// G = unit*4 + gate (permuted). fp16 index within a timestep row:
//   idx = (G>>7)*128 + (G&15)*8 + ((G>>4)&7)
// so scan wave w, lane l reads ONE uint4 (8 fp16 = its 8 tiles at col l&15).
// ---------------------------------------------------------------------------
__global__ __launch_bounds__(512, 2)
void xproj_kernel(const float* __restrict__ x, const float* __restrict__ Wih,
                  const float* __restrict__ bih, const float* __restrict__ bhh,
                  _Float16* __restrict__ xp, int nrows)
{
  const int gp   = threadIdx.x;          // permuted gate index G
  const int unit = gp >> 2;
  const int gate = gp & 3;
  const int row  = gate * HID + unit;    // row in W_ih / bias
  const int sidx = ((gp >> 7) << 7) + ((gp & 15) << 3) + ((gp >> 4) & 7);

  half2f wi[32];
  {
    const float4* wr = (const float4*)(Wih + (size_t)row * DIN);
#pragma unroll
    for (int q = 0; q < 16; q++) {
      float4 v = wr[q];
      wi[2 * q + 0] = mk2(v.x, v.y);
      wi[2 * q + 1] = mk2(v.z, v.w);
    }
  }
  const float bias = bih[row] + bhh[row];

  __shared__ __align__(16) _Float16 xin[8 * DIN];

  const int rows_per_block = (nrows + (int)gridDim.x - 1) / (int)gridDim.x;
  const int r0 = blockIdx.x * rows_per_block;
  const int r1 = (r0 + rows_per_block < nrows) ? (r0 + rows_per_block) : nrows;

  const int rsub = threadIdx.x >> 6;  // 0..7
  const int dd   = threadIdx.x & 63;

  float vld = 0.f;
  if (r0 + rsub < nrows) vld = x[(size_t)(r0 + rsub) * DIN + dd];

  for (int r = r0; r < r1; r += 8) {
    barrier_lgkm();
    xin[rsub * DIN + dd] = (_Float16)vld;
    barrier_lgkm();
    int rn = r + 8 + rsub;
    if (rn < nrows) vld = x[(size_t)rn * DIN + dd];

    const uint4* xi4 = (const uint4*)xin;
#pragma unroll
    for (int k = 0; k < 8; k++) {
      if (r + k >= r1) break;
      const uint4* rowp = xi4 + k * (DIN / 8);
      float a[4] = {bias, 0.f, 0.f, 0.f};
#pragma unroll
      for (int q = 0; q < 8; q++) {
        uint4 hv = rowp[q];
        a[q & 3] = fdot2(as_h2(hv.x), wi[4 * q + 0], a[q & 3]);
        a[q & 3] = fdot2(as_h2(hv.y), wi[4 * q + 1], a[q & 3]);
        a[q & 3] = fdot2(as_h2(hv.z), wi[4 * q + 2], a[q & 3]);
        a[q & 3] = fdot2(as_h2(hv.w), wi[4 * q + 3], a[q & 3]);
      }
      xp[(size_t)(r + k) * G4 + sidx] = (_Float16)(a[0] + a[1] + a[2] + a[3]);
    }
  }
}

// ---------------------------------------------------------------------------
// Phase 2: MFMA scan. 64 blocks x 256 threads (4 waves, 1/SIMD).
// gates(512) = Whh(512x128) . h(128) via mfma_f32_16x16x32_f16 with ALL 16
// rows of A = h  =>  D[m][n] = gate[n] in EVERY lane/reg (layout-robust).
// Wave w owns 8 N-tiles (gates [128w,128w+128) in permuted order).
// acc initialized with xp (C-operand carries x-projection + bias).
// Lane picks its 2 tiles (s*2, s*2+1), activates its own gate type
// (gt = lane&3), quad-DPP regathers i,f,g,o; c,h replicated per quad.
// One LDS round-trip + one lgkm-only barrier per step.
// ---------------------------------------------------------------------------
__global__ __launch_bounds__(256, 1)
void lstm_scan6(const float* __restrict__ Whh,
                const float* __restrict__ h0, const float* __restrict__ c0,
                const _Float16* __restrict__ xp,
                float* __restrict__ out, int T)
{
  const int tid  = threadIdx.x;
  const int w    = tid >> 6;   // wave 0..3
  const int lane = tid & 63;
  const int s    = lane >> 4;  // 0..3
  const int col  = lane & 15;
  const int gt   = lane & 3;   // gate type of this lane's columns
  const int b    = blockIdx.x;

  // B-fragments: tile ti (N) x chunk kc (K). lane slot j holds
  // Whh[rowOf(G)][kc*32 + s*8 + j]  (same (s,j)->k map as the A-frag below).
  half8 bfr[8][4];
#pragma unroll
  for (int ti = 0; ti < 8; ti++) {
    const int G    = (w * 8 + ti) * 16 + col;   // permuted gate index
    const int unit = G >> 2;
    const int g_   = G & 3;
    const float* wrow = Whh + (size_t)(g_ * HID + unit) * HID;
#pragma unroll
    for (int kc = 0; kc < 4; kc++) {
      const float4* p = (const float4*)(wrow + kc * 32 + s * 8);
      bfr[ti][kc] = cvt8(p[0], p[1]);
    }
  }

  // activation constants for my gate type: act = mm*rcp(1+exp(kk*x)) + bb
  const float kk = (gt == 2) ? -2.f : -1.f;
  const float mm = (gt == 2) ?  2.f :  1.f;
  const float bb = (gt == 2) ? -1.f :  0.f;

  // my two units (slot A = tile s*2, slot B = tile s*2+1)
  const int u0 = w * 32 + s * 8 + (col >> 2);
  const int u1 = u0 + 4;

  __shared__ __align__(16) _Float16 h_sh[2][HID];

  float cA = c0[(size_t)b * HID + u0];
  float cB = c0[(size_t)b * HID + u1];
  if (tid < HID) h_sh[0][tid] = (_Float16)h0[(size_t)b * HID + tid];

  // xp: one uint4 (8 fp16, one per tile at my col) per step
  const uint4* xp4 = (const uint4*)xp;
  const size_t xbase = (size_t)b * T * (G4 / 8) + w * 16 + col;
  uint4 xq  = xp4[xbase];
  uint4 xq1 = (T > 1) ? xp4[xbase + 64] : xq;

  barrier_lgkm();

  const _Float16* rb = h_sh[0];
  _Float16*       wb = h_sh[1];

  for (int t = 0; t < T; ++t) {
    uint4 xq2 = xq1;
    if (t + 2 < T) xq2 = xp4[xbase + (size_t)(t + 2) * 64];

    // A-fragments: every lane loads h[kc*32 + s*8 .. +7] (rows identical)
    const uint4* h4 = (const uint4*)rb;
    half8 af0 = __builtin_bit_cast(half8, h4[0 * 4 + s]);
    half8 af1 = __builtin_bit_cast(half8, h4[1 * 4 + s]);
    half8 af2 = __builtin_bit_cast(half8, h4[2 * 4 + s]);
    half8 af3 = __builtin_bit_cast(half8, h4[3 * 4 + s]);

    // acc init = xp (C-operand): all 4 regs = xp[tile][col]
    half8 xh = __builtin_bit_cast(half8, xq);
    floatx4 acc[8];
#pragma unroll
    for (int ti = 0; ti < 8; ti++) {
      float xv = (float)xh[ti];
      acc[ti] = (floatx4){xv, xv, xv, xv};
    }

#pragma unroll
    for (int ti = 0; ti < 8; ti++)
      acc[ti] = __builtin_amdgcn_mfma_f32_16x16x32_f16(af0, bfr[ti][0], acc[ti], 0, 0, 0);
#pragma unroll
    for (int ti = 0; ti < 8; ti++)
      acc[ti] = __builtin_amdgcn_mfma_f32_16x16x32_f16(af1, bfr[ti][1], acc[ti], 0, 0, 0);
#pragma unroll
    for (int ti = 0; ti < 8; ti++)
      acc[ti] = __builtin_amdgcn_mfma_f32_16x16x32_f16(af2, bfr[ti][2], acc[ti], 0, 0, 0);
#pragma unroll
    for (int ti = 0; ti < 8; ti++)
      acc[ti] = __builtin_amdgcn_mfma_f32_16x16x32_f16(af3, bfr[ti][3], acc[ti], 0, 0, 0);

    // select my 2 tiles (tp = s*2, tp+1) -- static regs, branchless tree
    float e0 = (s & 1) ? acc[2][0] : acc[0][0];
    float e1 = (s & 1) ? acc[6][0] : acc[4][0];
    float vA = (s & 2) ? e1 : e0;
    float o0 = (s & 1) ? acc[3][0] : acc[1][0];
    float o1 = (s & 1) ? acc[7][0] : acc[5][0];
    float vB = (s & 2) ? o1 : o0;

    // activate my own gate type only
    float actA = fmaf(mm, __builtin_amdgcn_rcpf(1.0f + __expf(kk * vA)), bb);
    float actB = fmaf(mm, __builtin_amdgcn_rcpf(1.0f + __expf(kk * vB)), bb);

    // quad regather i,f,g,o (quad lanes = gate types 0..3 of one unit)
    float giA = dpp_bcast<QP_B0>(actA);
    float gfA = dpp_bcast<QP_B1>(actA);
    float ggA = dpp_bcast<QP_B2>(actA);
    float goA = dpp_bcast<QP_B3>(actA);
    float giB = dpp_bcast<QP_B0>(actB);
    float gfB = dpp_bcast<QP_B1>(actB);
    float ggB = dpp_bcast<QP_B2>(actB);
    float goB = dpp_bcast<QP_B3>(actB);

    cA = fmaf(gfA, cA, giA * ggA);
    cB = fmaf(gfB, cB, giB * ggB);
    float hA = goA * tanhf_fast(cA);
    float hB = goB * tanhf_fast(cB);

    if (gt == 0) {
      wb[u0] = (_Float16)hA;
      wb[u1] = (_Float16)hB;
    } else if (gt == 1) {
      const size_t obase = ((size_t)b * T + t) * HID;
      out[obase + u0] = hA;
      out[obase + u1] = hB;
    }

    barrier_lgkm();                     // vmcnt NOT drained
    const _Float16* tmp = rb; rb = wb; wb = (_Float16*)tmp;
    xq = xq1; xq1 = xq2;
  }
}

// ---------------------------------------------------------------------------
// Fallback (ws too small): inline x-proj, round-1 structure.
// ---------------------------------------------------------------------------
__global__ __launch_bounds__(512, 2)
void lstm_scan_fb(const float* __restrict__ x, const float* __restrict__ Wih,
                  const float* __restrict__ Whh,
                  const float* __restrict__ bih, const float* __restrict__ bhh,
                  const float* __restrict__ h0, const float* __restrict__ c0,
                  float* __restrict__ out, int T)
{
  const int g = threadIdx.x;
  const int b = blockIdx.x;

  half2f w[64];
  {
    const float4* wr = (const float4*)(Whh + (size_t)g * HID);
#pragma unroll
    for (int q = 0; q < 32; q++) {
      float4 v = wr[q];
      w[2 * q + 0] = mk2(v.x, v.y);
      w[2 * q + 1] = mk2(v.z, v.w);
    }
  }
  half2f wi[32];
  float bias;
  {
    const float4* wr = (const float4*)(Wih + (size_t)g * DIN);
#pragma unroll
    for (int q = 0; q < 16; q++) {
      float4 v = wr[q];
      wi[2 * q + 0] = mk2(v.x, v.y);
      wi[2 * q + 1] = mk2(v.z, v.w);
    }
    bias = bih[g] + bhh[g];
  }

  __shared__ __align__(16) _Float16 h_sh[HID];
  __shared__ __align__(16) _Float16 xin[DIN];
  __shared__ float pre[G4];

  float c = 0.f;
  if (g < HID) {
    c = c0[(size_t)b * HID + g];
    h_sh[g] = (_Float16)h0[(size_t)b * HID + g];
  }
  if (g < DIN) xin[g] = (_Float16)x[((size_t)b * T) * DIN + g];
  __syncthreads();

  const bool is_tanh_gate = (g >= 2 * HID) && (g < 3 * HID);

  for (int t = 0; t < T; ++t) {
    float a[4] = {0.f, 0.f, 0.f, 0.f};
    const uint4* h4 = (const uint4*)h_sh;
#pragma unroll
    for (int q = 0; q < 16; q++) {
      uint4 hv = h4[q];
      a[q & 3] = fdot2(as_h2(hv.x), w[4 * q + 0], a[q & 3]);
      a[q & 3] = fdot2(as_h2(hv.y), w[4 * q + 1], a[q & 3]);
      a[q & 3] = fdot2(as_h2(hv.z), w[4 * q + 2], a[q & 3]);
      a[q & 3] = fdot2(as_h2(hv.w), w[4 * q + 3], a[q & 3]);
    }
    const uint4* x4 = (const uint4*)xin;
#pragma unroll
    for (int q = 0; q < 8; q++) {
      uint4 hv = x4[q];
      a[q & 3] = fdot2(as_h2(hv.x), wi[4 * q + 0], a[q & 3]);
      a[q & 3] = fdot2(as_h2(hv.y), wi[4 * q + 1], a[q & 3]);
      a[q & 3] = fdot2(as_h2(hv.z), wi[4 * q + 2], a[q & 3]);
      a[q & 3] = fdot2(as_h2(hv.w), wi[4 * q + 3], a[q & 3]);
    }
    float preact = a[0] + a[1] + a[2] + a[3] + bias;
    float act = is_tanh_gate ? tanhf_fast(preact) : sigmoidf_fast(preact);
    pre[g] = act;
    __syncthreads();

    if (g < HID) {
      float i  = pre[g];
      float f  = pre[g + HID];
      float gg = pre[g + 2 * HID];
      float o  = pre[g + 3 * HID];
      c = f * c + i * gg;
      float h = o * tanhf_fast(c);
      out[((size_t)b * T + t) * HID + g] = h;
      h_sh[g] = (_Float16)h;
    } else if (g >= HID && g < HID + DIN) {
      int d = g - HID;
      if (t + 1 < T) xin[d] = (_Float16)x[((size_t)b * T + (t + 1)) * DIN + d];
    }
    __syncthreads();
  }
}

// ---------------------------------------------------------------------------
extern "C" void kernel_launch(void* const* d_in, const int* in_sizes, int n_in,
                              void* d_out, int out_size, void* d_ws, size_t ws_size,
                              hipStream_t stream)
{
  const float* x   = (const float*)d_in[0];
  const float* Wih = (const float*)d_in[1];
  const float* Whh = (const float*)d_in[2];
  const float* bih = (const float*)d_in[3];
  const float* bhh = (const float*)d_in[4];
  const float* h0  = (const float*)d_in[5];
  const float* c0  = (const float*)d_in[6];
  float* out = (float*)d_out;

  const int B = in_sizes[5] / HID;
  const int T = in_sizes[0] / (B * DIN);
  const int nrows = B * T;

  const size_t xp_bytes = (size_t)nrows * G4 * sizeof(_Float16);
  if (ws_size >= xp_bytes) {
    _Float16* xp = (_Float16*)d_ws;
    xproj_kernel<<<1024, 512, 0, stream>>>(x, Wih, bih, bhh, xp, nrows);
    lstm_scan6<<<B, 256, 0, stream>>>(Whh, h0, c0, xp, out, T);
  } else {
    lstm_scan_fb<<<B, 512, 0, stream>>>(x, Wih, Whh, bih, bhh, h0, c0, out, T);
  }
}